// Round 2
// baseline (399.366 us; speedup 1.0000x reference)
//
#include <hip/hip_runtime.h>
#include <hip/hip_bf16.h>
#include <stdint.h>

#define LEAKY 0.2f
#define MIX_BETA 0.5f
#define MIX_C 1.2f

__device__ __forceinline__ unsigned f2bf(float f) {
    unsigned u = __float_as_uint(f);
    return (u + 0x7fffu + ((u >> 16) & 1u)) >> 16;   // RNE
}
__device__ __forceinline__ unsigned pack2bf(float a, float b) {
    return f2bf(a) | (f2bf(b) << 16);
}

// ---------------- dtype detection ----------------
// flags[0]=1 -> float arrays are bf16 ; flags[1]=1 -> edge_index is int32
__global__ void k_detect(const void* x, const void* ei, int N, int* flags) {
    int lane = threadIdx.x;  // 64 threads
    const uint16_t* u = (const uint16_t*)x;
    uint16_t v = u[2 * lane];                 // low half if fp32, a full elem if bf16
    int ef = (v >> 7) & 0xFF;
    bool ok = (ef >= 90 && ef <= 140);        // plausible N(0,1) bf16 exponent
    unsigned long long all_ok = __ballot(ok);
    const unsigned long long* e64 = (const unsigned long long*)ei;
    unsigned long long ev = e64[lane];
    bool big = (ev >= (unsigned long long)N);  // int32 pairs pack to huge u64
    unsigned long long anybig = __ballot(big);
    if (lane == 0) {
        flags[0] = (all_ok == 0xFFFFFFFFFFFFFFFFull) ? 1 : 0;
        flags[1] = (anybig != 0ull) ? 1 : 0;
    }
}

// ---------------- canonicalize small float vectors to fp32 ----------------
__global__ void k_canon_small(const void* att_s, const void* att_d, const void* bias,
                              const int* flags, float* att_sf, float* att_df, float* biasf) {
    int t = threadIdx.x;  // 384 threads
    bool bf = flags[0] != 0;
    const void* in; float* out; int idx;
    if (t < 128)       { in = att_s; out = att_sf; idx = t; }
    else if (t < 256)  { in = att_d; out = att_df; idx = t - 128; }
    else               { in = bias;  out = biasf;  idx = t - 256; }
    float v;
    if (bf) v = __uint_as_float(((unsigned)((const uint16_t*)in)[idx]) << 16);
    else    v = ((const float*)in)[idx];
    out[idx] = v;
}

// ---------------- xp = x @ W  (fp32 compute, fp32 store) ----------------
__global__ __launch_bounds__(256) void k_gemm(const void* x, const void* W,
                                              const int* flags, int N,
                                              float* xpf) {
    __shared__ float ws[128 * 128];      // [k][c], 64 KiB
    __shared__ float xs[128][132];       // [row][k] +pad
    const bool bf = flags[0] != 0;
    const int t = threadIdx.x;
    const int row0 = blockIdx.x * 128;

    for (int s = t; s < 4096; s += 256) {
        float4 v;
        if (bf) {
            ushort4 q = ((const ushort4*)W)[s];
            v.x = __uint_as_float((unsigned)q.x << 16);
            v.y = __uint_as_float((unsigned)q.y << 16);
            v.z = __uint_as_float((unsigned)q.z << 16);
            v.w = __uint_as_float((unsigned)q.w << 16);
        } else {
            v = ((const float4*)W)[s];
        }
        ((float4*)ws)[s] = v;
    }
    for (int s = t; s < 4096; s += 256) {
        int r = s >> 5, kc = s & 31;
        int rr = row0 + r; if (rr >= N) rr = N - 1;
        size_t g = (size_t)rr * 128 + 4 * kc;
        float4 v;
        if (bf) {
            ushort4 q = *(const ushort4*)((const uint16_t*)x + g);
            v.x = __uint_as_float((unsigned)q.x << 16);
            v.y = __uint_as_float((unsigned)q.y << 16);
            v.z = __uint_as_float((unsigned)q.z << 16);
            v.w = __uint_as_float((unsigned)q.w << 16);
        } else {
            v = *(const float4*)((const float*)x + g);
        }
        *(float4*)&xs[r][4 * kc] = v;
    }
    __syncthreads();

    const int tx = t & 15, ty = t >> 4;
    const int c0 = tx * 8, r0 = ty * 8;
    float acc[8][8];
#pragma unroll
    for (int r = 0; r < 8; ++r)
#pragma unroll
        for (int j = 0; j < 8; ++j) acc[r][j] = 0.f;

    for (int k = 0; k < 128; k += 4) {
        float4 xv[8];
#pragma unroll
        for (int r = 0; r < 8; ++r) xv[r] = *(const float4*)&xs[r0 + r][k];
#pragma unroll
        for (int kk = 0; kk < 4; ++kk) {
            float4 wa = *(const float4*)&ws[(k + kk) * 128 + c0];
            float4 wb = *(const float4*)&ws[(k + kk) * 128 + c0 + 4];
#pragma unroll
            for (int r = 0; r < 8; ++r) {
                float xr = (kk == 0) ? xv[r].x : (kk == 1) ? xv[r].y : (kk == 2) ? xv[r].z : xv[r].w;
                acc[r][0] = fmaf(xr, wa.x, acc[r][0]);
                acc[r][1] = fmaf(xr, wa.y, acc[r][1]);
                acc[r][2] = fmaf(xr, wa.z, acc[r][2]);
                acc[r][3] = fmaf(xr, wa.w, acc[r][3]);
                acc[r][4] = fmaf(xr, wb.x, acc[r][4]);
                acc[r][5] = fmaf(xr, wb.y, acc[r][5]);
                acc[r][6] = fmaf(xr, wb.z, acc[r][6]);
                acc[r][7] = fmaf(xr, wb.w, acc[r][7]);
            }
        }
    }
#pragma unroll
    for (int r = 0; r < 8; ++r) {
        int rr = row0 + r0 + r;
        if (rr < N) {
            float* po = xpf + (size_t)rr * 128 + c0;
            *(float4*)po       = make_float4(acc[r][0], acc[r][1], acc[r][2], acc[r][3]);
            *(float4*)(po + 4) = make_float4(acc[r][4], acc[r][5], acc[r][6], acc[r][7]);
        }
    }
}

// ---------------- per-node attention logits ----------------
__global__ void k_avec(const float* xpf, const float* att_sf, const float* att_df,
                       int N, float* a_src, float* a_dst) {
    int t = blockIdx.x * blockDim.x + threadIdx.x;
    if (t >= N * 4) return;
    int n = t >> 2, h = t & 3;
    const float4* p = (const float4*)(xpf + (size_t)n * 128 + h * 32);
    float ss = 0.f, sd = 0.f;
#pragma unroll
    for (int q = 0; q < 8; ++q) {
        float4 v = p[q];
        int d = h * 32 + q * 4;
        ss = fmaf(v.x, att_sf[d], ss);     sd = fmaf(v.x, att_df[d], sd);
        ss = fmaf(v.y, att_sf[d + 1], ss); sd = fmaf(v.y, att_df[d + 1], sd);
        ss = fmaf(v.z, att_sf[d + 2], ss); sd = fmaf(v.z, att_df[d + 2], sd);
        ss = fmaf(v.w, att_sf[d + 3], ss); sd = fmaf(v.w, att_df[d + 3], sd);
    }
    a_src[t] = ss;
    a_dst[t] = sd;
}

// ---------------- CSR build ----------------
__global__ void k_hist(const void* ei, int E, const int* flags, int* cnt) {
    bool is32 = flags[1] != 0;
    int stride = gridDim.x * blockDim.x;
    for (int i = blockIdx.x * blockDim.x + threadIdx.x; i < E; i += stride) {
        int d = is32 ? ((const int*)ei)[E + i] : (int)((const long long*)ei)[E + i];
        atomicAdd(&cnt[d], 1);
    }
}

__global__ void k_scan1(const int* cnt, int N, int chunk, int* bsum) {
    __shared__ int sm[256];
    int t = threadIdx.x, b = blockIdx.x;
    int idx = b * chunk + t;
    sm[t] = (t < chunk && idx < N) ? cnt[idx] : 0;
    __syncthreads();
    for (int off = 128; off; off >>= 1) {
        if (t < off) sm[t] += sm[t + off];
        __syncthreads();
    }
    if (!t) bsum[b] = sm[0];
}

__global__ void k_scan2(const int* bsum, int* bbase) {
    __shared__ int sm[256];
    int t = threadIdx.x;
    sm[t] = bsum[t];
    __syncthreads();
    for (int off = 1; off < 256; off <<= 1) {
        int v = (t >= off) ? sm[t - off] : 0;
        __syncthreads();
        sm[t] += v;
        __syncthreads();
    }
    bbase[t] = (t > 0) ? sm[t - 1] : 0;
}

__global__ void k_scan3(const int* cnt, const int* bbase, int N, int chunk,
                        int* offs, int* cursor) {
    __shared__ int sm[256];
    int t = threadIdx.x, b = blockIdx.x;
    int idx = b * chunk + t;
    sm[t] = (t < chunk && idx < N) ? cnt[idx] : 0;
    __syncthreads();
    for (int off = 1; off < 256; off <<= 1) {
        int v = (t >= off) ? sm[t - off] : 0;
        __syncthreads();
        sm[t] += v;
        __syncthreads();
    }
    int excl = ((t > 0) ? sm[t - 1] : 0) + bbase[b];
    if (t < chunk && idx < N) { offs[idx] = excl; cursor[idx] = excl; }
    // no offs[N]: aggregate uses cursor[n] (== offs[n]+cnt[n] after scatter) as end
}

__global__ void k_scatter(const void* ei, int E, const int* flags, int* cursor, int* ssrc) {
    bool is32 = flags[1] != 0;
    int stride = gridDim.x * blockDim.x;
    for (int i = blockIdx.x * blockDim.x + threadIdx.x; i < E; i += stride) {
        int s, d;
        if (is32) {
            const int* p = (const int*)ei;
            s = p[i]; d = p[E + i];
        } else {
            const long long* p = (const long long*)ei;
            s = (int)p[i]; d = (int)p[E + i];
        }
        int pos = atomicAdd(&cursor[d], 1);
        ssrc[pos] = s;
    }
}

// ---------------- per-node aggregation: one wave per node ----------------
__global__ __launch_bounds__(256) void k_aggregate(
    const float* xpf, const float* a_src, const float* a_dst,
    const int* offs, const int* cursor, const int* ssrc, const float* biasf,
    const int* flags, int N, void* out) {
    int wid = (blockIdx.x * 256 + threadIdx.x) >> 6;
    int lane = threadIdx.x & 63;
    if (wid >= N) return;
    const int n = wid;
    const int h = lane >> 4;        // 2*lane in [32h, 32h+31]
    const int c0 = 2 * lane;

    float adst = a_dst[(size_t)n * 4 + h];
    float al = a_src[(size_t)n * 4 + h] + adst;      // self loop
    al = (al > 0.f) ? al : LEAKY * al;
    float e = __expf(al);
    float2 xw = *(const float2*)(xpf + (size_t)n * 128 + c0);
    float acc0 = e * xw.x, acc1 = e * xw.y, den = e;

    int beg = offs[n], end = cursor[n];   // end == offs[n]+cnt[n] after scatter
    int i = beg;
    int s_nxt = (i < end) ? ssrc[i] : 0;
    while (i < end) {
        int s = s_nxt;
        int j = i + 1;
        if (j < end) s_nxt = ssrc[j];
        float a2 = a_src[(size_t)s * 4 + h] + adst;
        float2 xw2 = *(const float2*)(xpf + (size_t)s * 128 + c0);
        a2 = (a2 > 0.f) ? a2 : LEAKY * a2;
        float e2 = __expf(a2);
        acc0 = fmaf(e2, xw2.x, acc0);
        acc1 = fmaf(e2, xw2.y, acc1);
        den += e2;
        i = j;
    }
    float inv = 1.f / (den + 1e-16f);
    float z0 = fmaf(acc0, inv, biasf[c0]);
    float z1 = fmaf(acc1, inv, biasf[c0 + 1]);
    float r0 = MIX_BETA * z0 + (MIX_C - MIX_BETA) * z0 / (1.f + __expf(-z0));
    float r1 = MIX_BETA * z1 + (MIX_C - MIX_BETA) * z1 / (1.f + __expf(-z1));
    if (flags[0]) {
        *(unsigned*)((uint16_t*)out + (size_t)n * 128 + c0) = pack2bf(r0, r1);
    } else {
        *(float2*)((float*)out + (size_t)n * 128 + c0) = make_float2(r0, r1);
    }
}

extern "C" void kernel_launch(void* const* d_in, const int* in_sizes, int n_in,
                              void* d_out, int out_size, void* d_ws, size_t ws_size,
                              hipStream_t stream) {
    const void* x     = d_in[0];
    const void* ei    = d_in[1];
    const void* W     = d_in[2];
    const void* att_s = d_in[3];
    const void* att_d = d_in[4];
    const void* bias  = d_in[5];
    const int N = in_sizes[0] / 128;
    const int E = in_sizes[1] / 2;

    char* ws = (char*)d_ws;
    size_t off = 0;
    auto alloc = [&](size_t bytes) -> void* {
        void* p = ws + off;
        off += (bytes + 255) & ~(size_t)255;
        return p;
    };
    int* flags    = (int*)alloc(16);
    int* ssrc     = (int*)alloc((size_t)E * 4);
    int* cnt      = (int*)alloc((size_t)N * 4);
    int* offs     = (int*)alloc((size_t)N * 4);
    int* cursor   = (int*)alloc((size_t)N * 4);
    int* bsum     = (int*)alloc(256 * 4);
    int* bbase    = (int*)alloc(256 * 4);
    float* xpf    = (float*)alloc((size_t)N * 128 * 4);
    float* a_src  = (float*)alloc((size_t)N * 4 * 4);
    float* a_dst  = (float*)alloc((size_t)N * 4 * 4);
    float* att_sf = (float*)alloc(128 * 4);
    float* att_df = (float*)alloc(128 * 4);
    float* biasf  = (float*)alloc(128 * 4);

    k_detect<<<1, 64, 0, stream>>>(x, ei, N, flags);
    k_canon_small<<<1, 384, 0, stream>>>(att_s, att_d, bias, flags, att_sf, att_df, biasf);
    k_gemm<<<(N + 127) / 128, 256, 0, stream>>>(x, W, flags, N, xpf);
    k_avec<<<(N * 4 + 255) / 256, 256, 0, stream>>>(xpf, att_sf, att_df, N, a_src, a_dst);
    hipMemsetAsync(cnt, 0, (size_t)N * 4, stream);
    k_hist<<<2048, 256, 0, stream>>>(ei, E, flags, cnt);
    int chunk = (N + 255) / 256;
    k_scan1<<<256, 256, 0, stream>>>(cnt, N, chunk, bsum);
    k_scan2<<<1, 256, 0, stream>>>(bsum, bbase);
    k_scan3<<<256, 256, 0, stream>>>(cnt, bbase, N, chunk, offs, cursor);
    k_scatter<<<2048, 256, 0, stream>>>(ei, E, flags, cursor, ssrc);
    k_aggregate<<<(N + 3) / 4, 256, 0, stream>>>(xpf, a_src, a_dst, offs, cursor, ssrc,
                                                 biasf, flags, N, d_out);
}

// Round 3
// 263.341 us; speedup vs baseline: 1.5165x; 1.5165x over previous
//
#include <hip/hip_runtime.h>
#include <hip/hip_bf16.h>
#include <stdint.h>

#define LEAKY 0.2f
#define MIX_BETA 0.5f
#define MIX_C 1.2f

#define BKT_BITS 9                 // 512 nodes per bucket
#define BKT_SZ   (1 << BKT_BITS)
#define NBMAX    128               // max buckets (N <= 65536)
#define CH       4096              // edges per k_bscatter block

__device__ __forceinline__ unsigned f2bf(float f) {
    unsigned u = __float_as_uint(f);
    return (u + 0x7fffu + ((u >> 16) & 1u)) >> 16;   // RNE
}
__device__ __forceinline__ unsigned pack2bf(float a, float b) {
    return f2bf(a) | (f2bf(b) << 16);
}

// ---------------- dtype detection ----------------
// flags[0]=1 -> float arrays are bf16 ; flags[1]=1 -> edge_index is int32
__global__ void k_detect(const void* x, const void* ei, int N, int* flags) {
    int lane = threadIdx.x;  // 64 threads
    const uint16_t* u = (const uint16_t*)x;
    uint16_t v = u[2 * lane];
    int ef = (v >> 7) & 0xFF;
    bool ok = (ef >= 90 && ef <= 140);
    unsigned long long all_ok = __ballot(ok);
    const unsigned long long* e64 = (const unsigned long long*)ei;
    unsigned long long ev = e64[lane];
    bool big = (ev >= (unsigned long long)N);
    unsigned long long anybig = __ballot(big);
    if (lane == 0) {
        flags[0] = (all_ok == 0xFFFFFFFFFFFFFFFFull) ? 1 : 0;
        flags[1] = (anybig != 0ull) ? 1 : 0;
    }
}

// ---------------- canonicalize small float vectors to fp32 ----------------
__global__ void k_canon_small(const void* att_s, const void* att_d, const void* bias,
                              const int* flags, float* att_sf, float* att_df, float* biasf) {
    int t = threadIdx.x;  // 384 threads
    bool bf = flags[0] != 0;
    const void* in; float* out; int idx;
    if (t < 128)       { in = att_s; out = att_sf; idx = t; }
    else if (t < 256)  { in = att_d; out = att_df; idx = t - 128; }
    else               { in = bias;  out = biasf;  idx = t - 256; }
    float v;
    if (bf) v = __uint_as_float(((unsigned)((const uint16_t*)in)[idx]) << 16);
    else    v = ((const float*)in)[idx];
    out[idx] = v;
}

// ---------------- xp = x @ W  (fp32 compute, fp32 store) ----------------
__global__ __launch_bounds__(256) void k_gemm(const void* x, const void* W,
                                              const int* flags, int N,
                                              float* xpf) {
    __shared__ float ws[128 * 128];      // [k][c]
    __shared__ float xs[128][132];       // [row][k] +pad
    const bool bf = flags[0] != 0;
    const int t = threadIdx.x;
    const int row0 = blockIdx.x * 128;

    for (int s = t; s < 4096; s += 256) {
        float4 v;
        if (bf) {
            ushort4 q = ((const ushort4*)W)[s];
            v.x = __uint_as_float((unsigned)q.x << 16);
            v.y = __uint_as_float((unsigned)q.y << 16);
            v.z = __uint_as_float((unsigned)q.z << 16);
            v.w = __uint_as_float((unsigned)q.w << 16);
        } else {
            v = ((const float4*)W)[s];
        }
        ((float4*)ws)[s] = v;
    }
    for (int s = t; s < 4096; s += 256) {
        int r = s >> 5, kc = s & 31;
        int rr = row0 + r; if (rr >= N) rr = N - 1;
        size_t g = (size_t)rr * 128 + 4 * kc;
        float4 v;
        if (bf) {
            ushort4 q = *(const ushort4*)((const uint16_t*)x + g);
            v.x = __uint_as_float((unsigned)q.x << 16);
            v.y = __uint_as_float((unsigned)q.y << 16);
            v.z = __uint_as_float((unsigned)q.z << 16);
            v.w = __uint_as_float((unsigned)q.w << 16);
        } else {
            v = *(const float4*)((const float*)x + g);
        }
        *(float4*)&xs[r][4 * kc] = v;
    }
    __syncthreads();

    const int tx = t & 15, ty = t >> 4;
    const int c0 = tx * 8, r0 = ty * 8;
    float acc[8][8];
#pragma unroll
    for (int r = 0; r < 8; ++r)
#pragma unroll
        for (int j = 0; j < 8; ++j) acc[r][j] = 0.f;

    for (int k = 0; k < 128; k += 4) {
        float4 xv[8];
#pragma unroll
        for (int r = 0; r < 8; ++r) xv[r] = *(const float4*)&xs[r0 + r][k];
#pragma unroll
        for (int kk = 0; kk < 4; ++kk) {
            float4 wa = *(const float4*)&ws[(k + kk) * 128 + c0];
            float4 wb = *(const float4*)&ws[(k + kk) * 128 + c0 + 4];
#pragma unroll
            for (int r = 0; r < 8; ++r) {
                float xr = (kk == 0) ? xv[r].x : (kk == 1) ? xv[r].y : (kk == 2) ? xv[r].z : xv[r].w;
                acc[r][0] = fmaf(xr, wa.x, acc[r][0]);
                acc[r][1] = fmaf(xr, wa.y, acc[r][1]);
                acc[r][2] = fmaf(xr, wa.z, acc[r][2]);
                acc[r][3] = fmaf(xr, wa.w, acc[r][3]);
                acc[r][4] = fmaf(xr, wb.x, acc[r][4]);
                acc[r][5] = fmaf(xr, wb.y, acc[r][5]);
                acc[r][6] = fmaf(xr, wb.z, acc[r][6]);
                acc[r][7] = fmaf(xr, wb.w, acc[r][7]);
            }
        }
    }
#pragma unroll
    for (int r = 0; r < 8; ++r) {
        int rr = row0 + r0 + r;
        if (rr < N) {
            float* po = xpf + (size_t)rr * 128 + c0;
            *(float4*)po       = make_float4(acc[r][0], acc[r][1], acc[r][2], acc[r][3]);
            *(float4*)(po + 4) = make_float4(acc[r][4], acc[r][5], acc[r][6], acc[r][7]);
        }
    }
}

// ---------------- per-node attention logits ----------------
__global__ void k_avec(const float* xpf, const float* att_sf, const float* att_df,
                       int N, float* a_src, float* a_dst) {
    int t = blockIdx.x * blockDim.x + threadIdx.x;
    if (t >= N * 4) return;
    int n = t >> 2, h = t & 3;
    const float4* p = (const float4*)(xpf + (size_t)n * 128 + h * 32);
    float ss = 0.f, sd = 0.f;
#pragma unroll
    for (int q = 0; q < 8; ++q) {
        float4 v = p[q];
        int d = h * 32 + q * 4;
        ss = fmaf(v.x, att_sf[d], ss);     sd = fmaf(v.x, att_df[d], sd);
        ss = fmaf(v.y, att_sf[d + 1], ss); sd = fmaf(v.y, att_df[d + 1], sd);
        ss = fmaf(v.z, att_sf[d + 2], ss); sd = fmaf(v.z, att_df[d + 2], sd);
        ss = fmaf(v.w, att_sf[d + 3], ss); sd = fmaf(v.w, att_df[d + 3], sd);
    }
    a_src[t] = ss;
    a_dst[t] = sd;
}

// ---------------- bucket counting sort: level 1 counts ----------------
__global__ void k_bcount(const void* ei, int E, const int* flags, int nb, int* gbcnt) {
    __shared__ int lcnt[NBMAX];
    const bool is32 = flags[1] != 0;
    int t = threadIdx.x;
    for (int s = t; s < nb; s += blockDim.x) lcnt[s] = 0;
    __syncthreads();
    int stride = gridDim.x * blockDim.x;
    for (int i = blockIdx.x * blockDim.x + t; i < E; i += stride) {
        int d = is32 ? ((const int*)ei)[E + i] : (int)((const long long*)ei)[E + i];
        atomicAdd(&lcnt[d >> BKT_BITS], 1);
    }
    __syncthreads();
    for (int s = t; s < nb; s += blockDim.x)
        if (lcnt[s]) atomicAdd(&gbcnt[s], lcnt[s]);
}

// ---------------- level-1 scan (single block, 128 threads) ----------------
__global__ void k_bscan(const int* gbcnt, int nb, int* gbbase, int* gbcursor) {
    __shared__ int sm[NBMAX];
    int t = threadIdx.x;
    sm[t] = (t < nb) ? gbcnt[t] : 0;
    __syncthreads();
    for (int o = 1; o < NBMAX; o <<= 1) {
        int v = (t >= o) ? sm[t - o] : 0;
        __syncthreads();
        sm[t] += v;
        __syncthreads();
    }
    if (t < nb) {
        int excl = (t > 0) ? sm[t - 1] : 0;
        gbbase[t] = excl;
        gbcursor[t] = excl;
    }
}

// ---------------- level-1 scatter with LDS staging (coalesced flush) ----------------
__global__ __launch_bounds__(256) void k_bscatter(const void* ei, int E, const int* flags,
                                                  int nb, int* gbcursor, unsigned* entries) {
    __shared__ int lcnt[NBMAX];
    __shared__ int loff[NBMAX];
    __shared__ int lbase[NBMAX];
    __shared__ int wcur[NBMAX];
    __shared__ unsigned st[CH];
    __shared__ uint8_t bb[CH];
    const bool is32 = flags[1] != 0;
    const int t = threadIdx.x;
    const int chunk0 = blockIdx.x * CH;
    const int nvalid = min(CH, E - chunk0);

    for (int s = t; s < nb; s += 256) { lcnt[s] = 0; wcur[s] = 0; }
    __syncthreads();
    // phase a: local bucket histogram
    for (int k = 0; k < CH; k += 256) {
        int i = chunk0 + k + t;
        if (i < E) {
            int d = is32 ? ((const int*)ei)[E + i] : (int)((const long long*)ei)[E + i];
            atomicAdd(&lcnt[d >> BKT_BITS], 1);
        }
    }
    __syncthreads();
    // phase b: reserve global runs + local exclusive scan
    {
        int v = (t < NBMAX) ? lcnt[t] : 0;
        __shared__ int sc[NBMAX];
        if (t < NBMAX) sc[t] = v;
        __syncthreads();
        for (int o = 1; o < NBMAX; o <<= 1) {
            int w = (t < NBMAX && t >= o) ? sc[t - o] : 0;
            __syncthreads();
            if (t < NBMAX) sc[t] += w;
            __syncthreads();
        }
        if (t < nb) {
            loff[t] = sc[t] - lcnt[t];              // exclusive
            if (lcnt[t]) lbase[t] = atomicAdd(&gbcursor[t], lcnt[t]);
        }
    }
    __syncthreads();
    // phase c: stage entries grouped by bucket
    for (int k = 0; k < CH; k += 256) {
        int i = chunk0 + k + t;
        if (i < E) {
            int s, d;
            if (is32) { const int* p = (const int*)ei; s = p[i]; d = p[E + i]; }
            else { const long long* p = (const long long*)ei; s = (int)p[i]; d = (int)p[E + i]; }
            int b = d >> BKT_BITS;
            int slot = atomicAdd(&wcur[b], 1);
            int pos = loff[b] + slot;
            st[pos] = (unsigned)s | ((unsigned)(d & (BKT_SZ - 1)) << 17);
            bb[pos] = (uint8_t)b;
        }
    }
    __syncthreads();
    // phase d: coalesced flush
    for (int s = t; s < nvalid; s += 256) {
        int b = bb[s];
        entries[lbase[b] + (s - loff[b])] = st[s];
    }
}

// ---------------- level-2: per-bucket node sort + offs/cnt ----------------
__global__ __launch_bounds__(1024) void k_fine(const unsigned* entries, const int* gbbase,
                                               const int* gbend, int N,
                                               int* offs, int* cnt, uint16_t* ssrc) {
    __shared__ int ncnt[BKT_SZ];
    __shared__ int nscan[BKT_SZ];
    __shared__ int wcur[BKT_SZ];
    const int b = blockIdx.x;
    const int t = threadIdx.x;
    const int node0 = b << BKT_BITS;
    const int beg = gbbase[b], end = gbend[b];

    if (t < BKT_SZ) ncnt[t] = 0;
    __syncthreads();
    // phase a: per-node histogram
    for (int i = beg + t; i < end; i += 1024)
        atomicAdd(&ncnt[entries[i] >> 17], 1);
    __syncthreads();
    // phase b: scan 512
    if (t < BKT_SZ) nscan[t] = ncnt[t];
    __syncthreads();
    for (int o = 1; o < BKT_SZ; o <<= 1) {
        int v = (t < BKT_SZ && t >= o) ? nscan[t - o] : 0;
        __syncthreads();
        if (t < BKT_SZ) nscan[t] += v;
        __syncthreads();
    }
    if (t < BKT_SZ) {
        int excl = nscan[t] - ncnt[t];
        wcur[t] = excl;
        int node = node0 + t;
        if (node < N) {
            offs[node] = beg + excl;
            cnt[node] = ncnt[t];
        }
    }
    __syncthreads();
    // phase c: fine scatter (all writes within this bucket's window)
    for (int i = beg + t; i < end; i += 1024) {
        unsigned e = entries[i];
        int dlo = e >> 17;
        int slot = atomicAdd(&wcur[dlo], 1);
        ssrc[beg + slot] = (uint16_t)(e & 0xFFFFu);
    }
}

// ---------------- per-node aggregation: one wave per node ----------------
__global__ __launch_bounds__(256) void k_aggregate(
    const float* xpf, const float* a_src, const float* a_dst,
    const int* offs, const int* cnt, const uint16_t* ssrc, const float* biasf,
    const int* flags, int N, void* out) {
    int wid = (blockIdx.x * 256 + threadIdx.x) >> 6;
    int lane = threadIdx.x & 63;
    if (wid >= N) return;
    const int n = wid;
    const int h = lane >> 4;        // 2*lane in [32h, 32h+31]
    const int c0 = 2 * lane;

    float adst = a_dst[(size_t)n * 4 + h];
    float al = a_src[(size_t)n * 4 + h] + adst;      // self loop
    al = (al > 0.f) ? al : LEAKY * al;
    float e = __expf(al);
    float2 xw = *(const float2*)(xpf + (size_t)n * 128 + c0);
    float acc0 = e * xw.x, acc1 = e * xw.y, den = e;

    int beg = offs[n], end = beg + cnt[n];
    int i = beg;
    int s_nxt = (i < end) ? (int)ssrc[i] : 0;
    while (i < end) {
        int s = s_nxt;
        int j = i + 1;
        if (j < end) s_nxt = (int)ssrc[j];
        float a2 = a_src[(size_t)s * 4 + h] + adst;
        float2 xw2 = *(const float2*)(xpf + (size_t)s * 128 + c0);
        a2 = (a2 > 0.f) ? a2 : LEAKY * a2;
        float e2 = __expf(a2);
        acc0 = fmaf(e2, xw2.x, acc0);
        acc1 = fmaf(e2, xw2.y, acc1);
        den += e2;
        i = j;
    }
    float inv = 1.f / (den + 1e-16f);
    float z0 = fmaf(acc0, inv, biasf[c0]);
    float z1 = fmaf(acc1, inv, biasf[c0 + 1]);
    float r0 = MIX_BETA * z0 + (MIX_C - MIX_BETA) * z0 / (1.f + __expf(-z0));
    float r1 = MIX_BETA * z1 + (MIX_C - MIX_BETA) * z1 / (1.f + __expf(-z1));
    if (flags[0]) {
        *(unsigned*)((uint16_t*)out + (size_t)n * 128 + c0) = pack2bf(r0, r1);
    } else {
        *(float2*)((float*)out + (size_t)n * 128 + c0) = make_float2(r0, r1);
    }
}

extern "C" void kernel_launch(void* const* d_in, const int* in_sizes, int n_in,
                              void* d_out, int out_size, void* d_ws, size_t ws_size,
                              hipStream_t stream) {
    const void* x     = d_in[0];
    const void* ei    = d_in[1];
    const void* W     = d_in[2];
    const void* att_s = d_in[3];
    const void* att_d = d_in[4];
    const void* bias  = d_in[5];
    const int N = in_sizes[0] / 128;
    const int E = in_sizes[1] / 2;
    const int NB = (N + BKT_SZ - 1) >> BKT_BITS;

    char* ws = (char*)d_ws;
    size_t off = 0;
    auto alloc = [&](size_t bytes) -> void* {
        void* p = ws + off;
        off += (bytes + 255) & ~(size_t)255;
        return p;
    };
    int* flags        = (int*)alloc(16);
    unsigned* entries = (unsigned*)alloc((size_t)E * 4);
    uint16_t* ssrc    = (uint16_t*)alloc((size_t)E * 2);
    int* gbcnt        = (int*)alloc(NBMAX * 4);
    int* gbbase       = (int*)alloc(NBMAX * 4);
    int* gbcursor     = (int*)alloc(NBMAX * 4);
    int* offs         = (int*)alloc((size_t)N * 4);
    int* cnt          = (int*)alloc((size_t)N * 4);
    float* xpf        = (float*)alloc((size_t)N * 128 * 4);
    float* a_src      = (float*)alloc((size_t)N * 4 * 4);
    float* a_dst      = (float*)alloc((size_t)N * 4 * 4);
    float* att_sf     = (float*)alloc(128 * 4);
    float* att_df     = (float*)alloc(128 * 4);
    float* biasf      = (float*)alloc(128 * 4);

    k_detect<<<1, 64, 0, stream>>>(x, ei, N, flags);
    k_canon_small<<<1, 384, 0, stream>>>(att_s, att_d, bias, flags, att_sf, att_df, biasf);
    k_gemm<<<(N + 127) / 128, 256, 0, stream>>>(x, W, flags, N, xpf);
    k_avec<<<(N * 4 + 255) / 256, 256, 0, stream>>>(xpf, att_sf, att_df, N, a_src, a_dst);
    hipMemsetAsync(gbcnt, 0, NBMAX * 4, stream);
    k_bcount<<<1024, 256, 0, stream>>>(ei, E, flags, NB, gbcnt);
    k_bscan<<<1, NBMAX, 0, stream>>>(gbcnt, NB, gbbase, gbcursor);
    k_bscatter<<<(E + CH - 1) / CH, 256, 0, stream>>>(ei, E, flags, NB, gbcursor, entries);
    k_fine<<<NB, 1024, 0, stream>>>(entries, gbbase, gbcursor, N, offs, cnt, ssrc);
    k_aggregate<<<(N + 3) / 4, 256, 0, stream>>>(xpf, a_src, a_dst, offs, cnt, ssrc,
                                                 biasf, flags, N, d_out);
}

// Round 4
// 200.027 us; speedup vs baseline: 1.9966x; 1.3165x over previous
//
#include <hip/hip_runtime.h>
#include <hip/hip_bf16.h>
#include <hip/hip_fp16.h>
#include <stdint.h>

#define LEAKY 0.2f
#define MIX_BETA 0.5f
#define MIX_C 1.2f

#define BKT_BITS 9                 // 512 nodes per bucket
#define BKT_SZ   (1 << BKT_BITS)
#define NBMAX    128               // max buckets (N <= 65536)
#define CH       4096              // edges per k_bscatter block

__device__ __forceinline__ unsigned f2bf(float f) {
    unsigned u = __float_as_uint(f);
    return (u + 0x7fffu + ((u >> 16) & 1u)) >> 16;   // RNE
}
__device__ __forceinline__ unsigned pack2bf(float a, float b) {
    return f2bf(a) | (f2bf(b) << 16);
}
__device__ __forceinline__ float2 h2_to_f2(unsigned u) {
    __half2 h = *reinterpret_cast<__half2*>(&u);
    return __half22float2(h);
}
__device__ __forceinline__ unsigned pack2h(float a, float b) {
    return (unsigned)__half_as_ushort(__float2half(a)) |
           ((unsigned)__half_as_ushort(__float2half(b)) << 16);
}

// ---------------- dtype detection ----------------
// flags[0]=1 -> float arrays are bf16 ; flags[1]=1 -> edge_index is int32
__global__ void k_detect(const void* x, const void* ei, int N, int* flags) {
    int lane = threadIdx.x;  // 64 threads
    const uint16_t* u = (const uint16_t*)x;
    uint16_t v = u[2 * lane];
    int ef = (v >> 7) & 0xFF;
    bool ok = (ef >= 90 && ef <= 140);
    unsigned long long all_ok = __ballot(ok);
    const unsigned long long* e64 = (const unsigned long long*)ei;
    unsigned long long ev = e64[lane];
    bool big = (ev >= (unsigned long long)N);
    unsigned long long anybig = __ballot(big);
    if (lane == 0) {
        flags[0] = (all_ok == 0xFFFFFFFFFFFFFFFFull) ? 1 : 0;
        flags[1] = (anybig != 0ull) ? 1 : 0;
    }
}

// ---------------- canonicalize small float vectors to fp32 ----------------
__global__ void k_canon_small(const void* att_s, const void* att_d, const void* bias,
                              const int* flags, float* att_sf, float* att_df, float* biasf) {
    int t = threadIdx.x;  // 384 threads
    bool bf = flags[0] != 0;
    const void* in; float* out; int idx;
    if (t < 128)       { in = att_s; out = att_sf; idx = t; }
    else if (t < 256)  { in = att_d; out = att_df; idx = t - 128; }
    else               { in = bias;  out = biasf;  idx = t - 256; }
    float v;
    if (bf) v = __uint_as_float(((unsigned)((const uint16_t*)in)[idx]) << 16);
    else    v = ((const float*)in)[idx];
    out[idx] = v;
}

// ---------------- xp = x @ W (fp32 compute, fp16 store) + fused attention logits ----
__global__ __launch_bounds__(256) void k_gemm(const void* x, const void* W,
                                              const float* att_sf, const float* att_df,
                                              const int* flags, int N,
                                              unsigned* xph, float* a_src, float* a_dst) {
    __shared__ float ws[128 * 128];      // [k][c]
    __shared__ float xs[128][132];       // [row][k] +pad
    __shared__ float asrc_t[128][4];
    __shared__ float adst_t[128][4];
    const bool bf = flags[0] != 0;
    const int t = threadIdx.x;
    const int row0 = blockIdx.x * 128;

    for (int s = t; s < 4096; s += 256) {
        float4 v;
        if (bf) {
            ushort4 q = ((const ushort4*)W)[s];
            v.x = __uint_as_float((unsigned)q.x << 16);
            v.y = __uint_as_float((unsigned)q.y << 16);
            v.z = __uint_as_float((unsigned)q.z << 16);
            v.w = __uint_as_float((unsigned)q.w << 16);
        } else {
            v = ((const float4*)W)[s];
        }
        ((float4*)ws)[s] = v;
    }
    for (int s = t; s < 4096; s += 256) {
        int r = s >> 5, kc = s & 31;
        int rr = row0 + r; if (rr >= N) rr = N - 1;
        size_t g = (size_t)rr * 128 + 4 * kc;
        float4 v;
        if (bf) {
            ushort4 q = *(const ushort4*)((const uint16_t*)x + g);
            v.x = __uint_as_float((unsigned)q.x << 16);
            v.y = __uint_as_float((unsigned)q.y << 16);
            v.z = __uint_as_float((unsigned)q.z << 16);
            v.w = __uint_as_float((unsigned)q.w << 16);
        } else {
            v = *(const float4*)((const float*)x + g);
        }
        *(float4*)&xs[r][4 * kc] = v;
    }
    __syncthreads();

    const int tx = t & 15, ty = t >> 4;
    const int c0 = tx * 8, r0 = ty * 8;
    float acc[8][8];
#pragma unroll
    for (int r = 0; r < 8; ++r)
#pragma unroll
        for (int j = 0; j < 8; ++j) acc[r][j] = 0.f;

    for (int k = 0; k < 128; k += 4) {
        float4 xv[8];
#pragma unroll
        for (int r = 0; r < 8; ++r) xv[r] = *(const float4*)&xs[r0 + r][k];
#pragma unroll
        for (int kk = 0; kk < 4; ++kk) {
            float4 wa = *(const float4*)&ws[(k + kk) * 128 + c0];
            float4 wb = *(const float4*)&ws[(k + kk) * 128 + c0 + 4];
#pragma unroll
            for (int r = 0; r < 8; ++r) {
                float xr = (kk == 0) ? xv[r].x : (kk == 1) ? xv[r].y : (kk == 2) ? xv[r].z : xv[r].w;
                acc[r][0] = fmaf(xr, wa.x, acc[r][0]);
                acc[r][1] = fmaf(xr, wa.y, acc[r][1]);
                acc[r][2] = fmaf(xr, wa.z, acc[r][2]);
                acc[r][3] = fmaf(xr, wa.w, acc[r][3]);
                acc[r][4] = fmaf(xr, wb.x, acc[r][4]);
                acc[r][5] = fmaf(xr, wb.y, acc[r][5]);
                acc[r][6] = fmaf(xr, wb.z, acc[r][6]);
                acc[r][7] = fmaf(xr, wb.w, acc[r][7]);
            }
        }
    }

    // epilogue 1: fp16 xp store
#pragma unroll
    for (int r = 0; r < 8; ++r) {
        int rr = row0 + r0 + r;
        if (rr < N) {
            int4 ov;
            unsigned* po = (unsigned*)&ov;
#pragma unroll
            for (int j = 0; j < 4; ++j) po[j] = pack2h(acc[r][2 * j], acc[r][2 * j + 1]);
            *(int4*)((uint16_t*)xph + (size_t)rr * 128 + c0) = ov;
        }
    }

    // epilogue 2: fused attention logits.
    // head = tx>>2; cols c0..c0+7 lie within that head (c0 = tx*8, 8 | 32).
    const int head = tx >> 2;
    const int cb = (tx & 3) * 8;   // offset within head's 32 dims
    float sA[8], sD[8];
#pragma unroll
    for (int j = 0; j < 8; ++j) {
        sA[j] = att_sf[head * 32 + cb + j];
        sD[j] = att_df[head * 32 + cb + j];
    }
#pragma unroll
    for (int r = 0; r < 8; ++r) {
        float ps = 0.f, pd = 0.f;
#pragma unroll
        for (int j = 0; j < 8; ++j) {
            ps = fmaf(acc[r][j], sA[j], ps);
            pd = fmaf(acc[r][j], sD[j], pd);
        }
        // reduce over the 4 threads of this head's tx-quad (adjacent lanes)
        ps += __shfl_xor(ps, 1); ps += __shfl_xor(ps, 2);
        pd += __shfl_xor(pd, 1); pd += __shfl_xor(pd, 2);
        if ((tx & 3) == 0) {
            asrc_t[r0 + r][head] = ps;
            adst_t[r0 + r][head] = pd;
        }
    }
    __syncthreads();
    for (int idx = t; idx < 512; idx += 256) {
        int lr = idx >> 2, hh = idx & 3;
        int rr = row0 + lr;
        if (rr < N) {
            a_src[(size_t)rr * 4 + hh] = asrc_t[lr][hh];
            a_dst[(size_t)rr * 4 + hh] = adst_t[lr][hh];
        }
    }
}

// ---------------- level-1 scatter into fixed-capacity bucket segments ----------------
__global__ __launch_bounds__(256) void k_bscatter(const void* ei, int E, const int* flags,
                                                  int nb, int cap, int* gbcursor,
                                                  unsigned* entries) {
    __shared__ int lcnt[NBMAX];
    __shared__ int loff[NBMAX];
    __shared__ int lbase[NBMAX];
    __shared__ int wcur[NBMAX];
    __shared__ int sc[NBMAX];
    __shared__ unsigned st[CH];
    __shared__ uint8_t bb[CH];
    const bool is32 = flags[1] != 0;
    const int t = threadIdx.x;
    const int chunk0 = blockIdx.x * CH;
    const int nvalid = min(CH, E - chunk0);

    for (int s = t; s < NBMAX; s += 256) { lcnt[s] = 0; wcur[s] = 0; }
    __syncthreads();
    // phase a: local bucket histogram
    for (int k = 0; k < CH; k += 256) {
        int i = chunk0 + k + t;
        if (i < E) {
            int d = is32 ? ((const int*)ei)[E + i] : (int)((const long long*)ei)[E + i];
            atomicAdd(&lcnt[d >> BKT_BITS], 1);
        }
    }
    __syncthreads();
    // phase b: local exclusive scan + reserve global runs
    if (t < NBMAX) sc[t] = lcnt[t];
    __syncthreads();
    for (int o = 1; o < NBMAX; o <<= 1) {
        int w = (t < NBMAX && t >= o) ? sc[t - o] : 0;
        __syncthreads();
        if (t < NBMAX) sc[t] += w;
        __syncthreads();
    }
    if (t < nb) {
        loff[t] = sc[t] - lcnt[t];
        if (lcnt[t]) {
            int base = atomicAdd(&gbcursor[t], lcnt[t]);
            if (base + lcnt[t] > cap) base = cap - lcnt[t];   // memory-safety clamp
            lbase[t] = base;
        }
    }
    __syncthreads();
    // phase c: stage entries grouped by bucket
    for (int k = 0; k < CH; k += 256) {
        int i = chunk0 + k + t;
        if (i < E) {
            int s, d;
            if (is32) { const int* p = (const int*)ei; s = p[i]; d = p[E + i]; }
            else { const long long* p = (const long long*)ei; s = (int)p[i]; d = (int)p[E + i]; }
            int b = d >> BKT_BITS;
            int slot = atomicAdd(&wcur[b], 1);
            int pos = loff[b] + slot;
            st[pos] = (unsigned)s | ((unsigned)(d & (BKT_SZ - 1)) << 17);
            bb[pos] = (uint8_t)b;
        }
    }
    __syncthreads();
    // phase d: coalesced flush into segment b*cap
    for (int s = t; s < nvalid; s += 256) {
        int b = bb[s];
        entries[(size_t)b * cap + lbase[b] + (s - loff[b])] = st[s];
    }
}

// ---------------- level-2: per-bucket node sort + offs/cnt ----------------
__global__ __launch_bounds__(1024) void k_fine(const unsigned* entries, const int* gbcursor,
                                               int cap, int N,
                                               int* offs, int* cnt, uint16_t* ssrc) {
    __shared__ int ncnt[BKT_SZ];
    __shared__ int nscan[BKT_SZ];
    __shared__ int wcur[BKT_SZ];
    const int b = blockIdx.x;
    const int t = threadIdx.x;
    const int node0 = b << BKT_BITS;
    const size_t eb = (size_t)b * cap;
    const int count = min(gbcursor[b], cap);

    if (t < BKT_SZ) ncnt[t] = 0;
    __syncthreads();
    for (int i = t; i < count; i += 1024)
        atomicAdd(&ncnt[entries[eb + i] >> 17], 1);
    __syncthreads();
    if (t < BKT_SZ) nscan[t] = ncnt[t];
    __syncthreads();
    for (int o = 1; o < BKT_SZ; o <<= 1) {
        int v = (t < BKT_SZ && t >= o) ? nscan[t - o] : 0;
        __syncthreads();
        if (t < BKT_SZ) nscan[t] += v;
        __syncthreads();
    }
    if (t < BKT_SZ) {
        int excl = nscan[t] - ncnt[t];
        wcur[t] = excl;
        int node = node0 + t;
        if (node < N) {
            offs[node] = (int)eb + excl;
            cnt[node] = ncnt[t];
        }
    }
    __syncthreads();
    for (int i = t; i < count; i += 1024) {
        unsigned e = entries[eb + i];
        int dlo = e >> 17;
        int slot = atomicAdd(&wcur[dlo], 1);
        ssrc[eb + slot] = (uint16_t)(e & 0xFFFFu);
    }
}

// ---------------- per-node aggregation: one wave per node ----------------
__global__ __launch_bounds__(256) void k_aggregate(
    const unsigned* xph, const float* a_src, const float* a_dst,
    const int* offs, const int* cnt, const uint16_t* ssrc, const float* biasf,
    const int* flags, int N, void* out) {
    int wid = (blockIdx.x * 256 + threadIdx.x) >> 6;
    int lane = threadIdx.x & 63;
    if (wid >= N) return;
    const int n = wid;
    const int h = lane >> 4;        // 2*lane in [32h, 32h+31]
    const int c0 = 2 * lane;

    float adst = a_dst[(size_t)n * 4 + h];
    float al = a_src[(size_t)n * 4 + h] + adst;      // self loop
    al = (al > 0.f) ? al : LEAKY * al;
    float e = __expf(al);
    float2 xw = h2_to_f2(xph[(size_t)n * 64 + lane]);
    float acc0 = e * xw.x, acc1 = e * xw.y, den = e;

    const int beg = offs[n];
    const int endp = beg + cnt[n];
    int i = beg;
    for (; i + 2 <= endp; i += 2) {
        int s0 = ssrc[i], s1 = ssrc[i + 1];
        unsigned w0 = xph[(size_t)s0 * 64 + lane];
        unsigned w1 = xph[(size_t)s1 * 64 + lane];
        float b0 = a_src[(size_t)s0 * 4 + h] + adst;
        float b1 = a_src[(size_t)s1 * 4 + h] + adst;
        b0 = (b0 > 0.f) ? b0 : LEAKY * b0;
        b1 = (b1 > 0.f) ? b1 : LEAKY * b1;
        float e0 = __expf(b0), e1 = __expf(b1);
        float2 f0 = h2_to_f2(w0), f1 = h2_to_f2(w1);
        acc0 = fmaf(e0, f0.x, acc0); acc1 = fmaf(e0, f0.y, acc1);
        acc0 = fmaf(e1, f1.x, acc0); acc1 = fmaf(e1, f1.y, acc1);
        den += e0 + e1;
    }
    if (i < endp) {
        int s0 = ssrc[i];
        unsigned w0 = xph[(size_t)s0 * 64 + lane];
        float b0 = a_src[(size_t)s0 * 4 + h] + adst;
        b0 = (b0 > 0.f) ? b0 : LEAKY * b0;
        float e0 = __expf(b0);
        float2 f0 = h2_to_f2(w0);
        acc0 = fmaf(e0, f0.x, acc0); acc1 = fmaf(e0, f0.y, acc1);
        den += e0;
    }
    float inv = 1.f / (den + 1e-16f);
    float z0 = fmaf(acc0, inv, biasf[c0]);
    float z1 = fmaf(acc1, inv, biasf[c0 + 1]);
    float r0 = MIX_BETA * z0 + (MIX_C - MIX_BETA) * z0 / (1.f + __expf(-z0));
    float r1 = MIX_BETA * z1 + (MIX_C - MIX_BETA) * z1 / (1.f + __expf(-z1));
    if (flags[0]) {
        *(unsigned*)((uint16_t*)out + (size_t)n * 128 + c0) = pack2bf(r0, r1);
    } else {
        *(float2*)((float*)out + (size_t)n * 128 + c0) = make_float2(r0, r1);
    }
}

extern "C" void kernel_launch(void* const* d_in, const int* in_sizes, int n_in,
                              void* d_out, int out_size, void* d_ws, size_t ws_size,
                              hipStream_t stream) {
    const void* x     = d_in[0];
    const void* ei    = d_in[1];
    const void* W     = d_in[2];
    const void* att_s = d_in[3];
    const void* att_d = d_in[4];
    const void* bias  = d_in[5];
    const int N = in_sizes[0] / 128;
    const int E = in_sizes[1] / 2;
    const int NB = (N + BKT_SZ - 1) >> BKT_BITS;
    const int cap = E / NB + E / (4 * NB) + 2048;

    char* ws = (char*)d_ws;
    size_t off = 0;
    auto alloc = [&](size_t bytes) -> void* {
        void* p = ws + off;
        off += (bytes + 255) & ~(size_t)255;
        return p;
    };
    int* flags        = (int*)alloc(16);
    unsigned* entries = (unsigned*)alloc((size_t)NB * cap * 4);
    uint16_t* ssrc    = (uint16_t*)alloc((size_t)NB * cap * 2);
    int* gbcursor     = (int*)alloc(NBMAX * 4);
    int* offs         = (int*)alloc((size_t)N * 4);
    int* cnt          = (int*)alloc((size_t)N * 4);
    unsigned* xph     = (unsigned*)alloc((size_t)N * 64 * 4);   // fp16 x2 packed
    float* a_src      = (float*)alloc((size_t)N * 4 * 4);
    float* a_dst      = (float*)alloc((size_t)N * 4 * 4);
    float* att_sf     = (float*)alloc(128 * 4);
    float* att_df     = (float*)alloc(128 * 4);
    float* biasf      = (float*)alloc(128 * 4);

    k_detect<<<1, 64, 0, stream>>>(x, ei, N, flags);
    k_canon_small<<<1, 384, 0, stream>>>(att_s, att_d, bias, flags, att_sf, att_df, biasf);
    hipMemsetAsync(gbcursor, 0, NBMAX * 4, stream);
    k_gemm<<<(N + 127) / 128, 256, 0, stream>>>(x, W, att_sf, att_df, flags, N,
                                                xph, a_src, a_dst);
    k_bscatter<<<(E + CH - 1) / CH, 256, 0, stream>>>(ei, E, flags, NB, cap, gbcursor, entries);
    k_fine<<<NB, 1024, 0, stream>>>(entries, gbcursor, cap, N, offs, cnt, ssrc);
    k_aggregate<<<(N + 3) / 4, 256, 0, stream>>>(xph, a_src, a_dst, offs, cnt, ssrc,
                                                 biasf, flags, N, d_out);
}

// Round 5
// 175.238 us; speedup vs baseline: 2.2790x; 1.1415x over previous
//
#include <hip/hip_runtime.h>
#include <hip/hip_bf16.h>
#include <hip/hip_fp16.h>
#include <stdint.h>

#define LEAKY 0.2f
#define MIX_BETA 0.5f
#define MIX_C 1.2f

#define BKT_BITS 8                 // 256 nodes per bucket
#define BKT_SZ   (1 << BKT_BITS)
#define NBMAX    256               // max buckets
#define CH       4096              // edges per k_bscatter block
#define EPT      16                // edges per thread in k_bscatter (CH/256)

__device__ __forceinline__ unsigned f2bf(float f) {
    unsigned u = __float_as_uint(f);
    return (u + 0x7fffu + ((u >> 16) & 1u)) >> 16;   // RNE
}
__device__ __forceinline__ unsigned pack2bf(float a, float b) {
    return f2bf(a) | (f2bf(b) << 16);
}
__device__ __forceinline__ float2 h2_to_f2(unsigned u) {
    __half2 h = *reinterpret_cast<__half2*>(&u);
    return __half22float2(h);
}
__device__ __forceinline__ unsigned pack2h(float a, float b) {
    return (unsigned)__half_as_ushort(__float2half(a)) |
           ((unsigned)__half_as_ushort(__float2half(b)) << 16);
}
__device__ __forceinline__ float leaky_exp(float v) {
    v = fmaxf(v, LEAKY * v);
    return __expf(v);
}

// ---------------- dtype detection ----------------
__global__ void k_detect(const void* x, const void* ei, int N, int* flags) {
    int lane = threadIdx.x;  // 64 threads
    const uint16_t* u = (const uint16_t*)x;
    uint16_t v = u[2 * lane];
    int ef = (v >> 7) & 0xFF;
    bool ok = (ef >= 90 && ef <= 140);
    unsigned long long all_ok = __ballot(ok);
    const unsigned long long* e64 = (const unsigned long long*)ei;
    unsigned long long ev = e64[lane];
    bool big = (ev >= (unsigned long long)N);
    unsigned long long anybig = __ballot(big);
    if (lane == 0) {
        flags[0] = (all_ok == 0xFFFFFFFFFFFFFFFFull) ? 1 : 0;
        flags[1] = (anybig != 0ull) ? 1 : 0;
    }
}

// ---------------- canonicalize small float vectors to fp32 ----------------
__global__ void k_canon_small(const void* att_s, const void* att_d, const void* bias,
                              const int* flags, float* att_sf, float* att_df, float* biasf) {
    int t = threadIdx.x;  // 384 threads
    bool bf = flags[0] != 0;
    const void* in; float* out; int idx;
    if (t < 128)       { in = att_s; out = att_sf; idx = t; }
    else if (t < 256)  { in = att_d; out = att_df; idx = t - 128; }
    else               { in = bias;  out = biasf;  idx = t - 256; }
    float v;
    if (bf) v = __uint_as_float(((unsigned)((const uint16_t*)in)[idx]) << 16);
    else    v = ((const float*)in)[idx];
    out[idx] = v;
}

// ---------------- xp = x @ W (fp32 compute, fp16 store) + fused attention logits ----
__global__ __launch_bounds__(256) void k_gemm(const void* x, const void* W,
                                              const float* att_sf, const float* att_df,
                                              const int* flags, int N,
                                              unsigned* xph, float* a_src, float* a_dst) {
    __shared__ float ws[128 * 128];      // [k][c]
    __shared__ float xs[128][132];       // [row][k] +pad
    __shared__ float asrc_t[128][4];
    __shared__ float adst_t[128][4];
    const bool bf = flags[0] != 0;
    const int t = threadIdx.x;
    const int row0 = blockIdx.x * 128;

    for (int s = t; s < 4096; s += 256) {
        float4 v;
        if (bf) {
            ushort4 q = ((const ushort4*)W)[s];
            v.x = __uint_as_float((unsigned)q.x << 16);
            v.y = __uint_as_float((unsigned)q.y << 16);
            v.z = __uint_as_float((unsigned)q.z << 16);
            v.w = __uint_as_float((unsigned)q.w << 16);
        } else {
            v = ((const float4*)W)[s];
        }
        ((float4*)ws)[s] = v;
    }
    for (int s = t; s < 4096; s += 256) {
        int r = s >> 5, kc = s & 31;
        int rr = row0 + r; if (rr >= N) rr = N - 1;
        size_t g = (size_t)rr * 128 + 4 * kc;
        float4 v;
        if (bf) {
            ushort4 q = *(const ushort4*)((const uint16_t*)x + g);
            v.x = __uint_as_float((unsigned)q.x << 16);
            v.y = __uint_as_float((unsigned)q.y << 16);
            v.z = __uint_as_float((unsigned)q.z << 16);
            v.w = __uint_as_float((unsigned)q.w << 16);
        } else {
            v = *(const float4*)((const float*)x + g);
        }
        *(float4*)&xs[r][4 * kc] = v;
    }
    __syncthreads();

    const int tx = t & 15, ty = t >> 4;
    const int c0 = tx * 8, r0 = ty * 8;
    float acc[8][8];
#pragma unroll
    for (int r = 0; r < 8; ++r)
#pragma unroll
        for (int j = 0; j < 8; ++j) acc[r][j] = 0.f;

    for (int k = 0; k < 128; k += 4) {
        float4 xv[8];
#pragma unroll
        for (int r = 0; r < 8; ++r) xv[r] = *(const float4*)&xs[r0 + r][k];
#pragma unroll
        for (int kk = 0; kk < 4; ++kk) {
            float4 wa = *(const float4*)&ws[(k + kk) * 128 + c0];
            float4 wb = *(const float4*)&ws[(k + kk) * 128 + c0 + 4];
#pragma unroll
            for (int r = 0; r < 8; ++r) {
                float xr = (kk == 0) ? xv[r].x : (kk == 1) ? xv[r].y : (kk == 2) ? xv[r].z : xv[r].w;
                acc[r][0] = fmaf(xr, wa.x, acc[r][0]);
                acc[r][1] = fmaf(xr, wa.y, acc[r][1]);
                acc[r][2] = fmaf(xr, wa.z, acc[r][2]);
                acc[r][3] = fmaf(xr, wa.w, acc[r][3]);
                acc[r][4] = fmaf(xr, wb.x, acc[r][4]);
                acc[r][5] = fmaf(xr, wb.y, acc[r][5]);
                acc[r][6] = fmaf(xr, wb.z, acc[r][6]);
                acc[r][7] = fmaf(xr, wb.w, acc[r][7]);
            }
        }
    }

    // epilogue 1: fp16 xp store
#pragma unroll
    for (int r = 0; r < 8; ++r) {
        int rr = row0 + r0 + r;
        if (rr < N) {
            int4 ov;
            unsigned* po = (unsigned*)&ov;
#pragma unroll
            for (int j = 0; j < 4; ++j) po[j] = pack2h(acc[r][2 * j], acc[r][2 * j + 1]);
            *(int4*)((uint16_t*)xph + (size_t)rr * 128 + c0) = ov;
        }
    }

    // epilogue 2: fused attention logits (head = tx>>2)
    const int head = tx >> 2;
    const int cb = (tx & 3) * 8;
    float sA[8], sD[8];
#pragma unroll
    for (int j = 0; j < 8; ++j) {
        sA[j] = att_sf[head * 32 + cb + j];
        sD[j] = att_df[head * 32 + cb + j];
    }
#pragma unroll
    for (int r = 0; r < 8; ++r) {
        float ps = 0.f, pd = 0.f;
#pragma unroll
        for (int j = 0; j < 8; ++j) {
            ps = fmaf(acc[r][j], sA[j], ps);
            pd = fmaf(acc[r][j], sD[j], pd);
        }
        ps += __shfl_xor(ps, 1); ps += __shfl_xor(ps, 2);
        pd += __shfl_xor(pd, 1); pd += __shfl_xor(pd, 2);
        if ((tx & 3) == 0) {
            asrc_t[r0 + r][head] = ps;
            adst_t[r0 + r][head] = pd;
        }
    }
    __syncthreads();
    for (int idx = t; idx < 512; idx += 256) {
        int lr = idx >> 2, hh = idx & 3;
        int rr = row0 + lr;
        if (rr < N) {
            a_src[(size_t)rr * 4 + hh] = asrc_t[lr][hh];
            a_dst[(size_t)rr * 4 + hh] = adst_t[lr][hh];
        }
    }
}

// ---------------- level-1 scatter into fixed-capacity bucket segments ----------------
__global__ __launch_bounds__(256) void k_bscatter(const void* ei, int E, const int* flags,
                                                  int nb, int cap, int* gbcursor,
                                                  unsigned* entries) {
    __shared__ int lcnt[NBMAX];
    __shared__ int loff[NBMAX];
    __shared__ int lbase[NBMAX];
    __shared__ int wcur[NBMAX];
    __shared__ int sc[NBMAX];
    __shared__ unsigned st[CH];
    __shared__ uint8_t bb[CH];
    const bool is32 = flags[1] != 0;
    const int t = threadIdx.x;
    const int chunk0 = blockIdx.x * CH;
    const int nvalid = min(CH, E - chunk0);

    int se[EPT], de[EPT];
    lcnt[t] = 0; wcur[t] = 0;
    __syncthreads();
    // phase a: load edges to regs + local bucket histogram
#pragma unroll
    for (int k = 0; k < EPT; ++k) {
        int i = chunk0 + k * 256 + t;
        if (i < E) {
            int s, d;
            if (is32) { const int* p = (const int*)ei; s = p[i]; d = p[E + i]; }
            else { const long long* p = (const long long*)ei; s = (int)p[i]; d = (int)p[E + i]; }
            se[k] = s; de[k] = d;
            atomicAdd(&lcnt[d >> BKT_BITS], 1);
        } else {
            de[k] = -1;
        }
    }
    __syncthreads();
    // phase b: local exclusive scan + reserve global runs
    sc[t] = lcnt[t];
    __syncthreads();
    for (int o = 1; o < NBMAX; o <<= 1) {
        int w = (t >= o) ? sc[t - o] : 0;
        __syncthreads();
        sc[t] += w;
        __syncthreads();
    }
    if (t < nb) {
        loff[t] = sc[t] - lcnt[t];
        if (lcnt[t]) {
            int base = atomicAdd(&gbcursor[t], lcnt[t]);
            if (base + lcnt[t] > cap) base = cap - lcnt[t];   // memory-safety clamp
            lbase[t] = base;
        }
    }
    __syncthreads();
    // phase c: stage entries grouped by bucket
#pragma unroll
    for (int k = 0; k < EPT; ++k) {
        int d = de[k];
        if (d >= 0) {
            int b = d >> BKT_BITS;
            int slot = atomicAdd(&wcur[b], 1);
            int pos = loff[b] + slot;
            st[pos] = (unsigned)se[k] | ((unsigned)(d & (BKT_SZ - 1)) << 17);
            bb[pos] = (uint8_t)b;
        }
    }
    __syncthreads();
    // phase d: coalesced flush into segment b*cap
    for (int s = t; s < nvalid; s += 256) {
        int b = bb[s];
        entries[(size_t)b * cap + lbase[b] + (s - loff[b])] = st[s];
    }
}

// ---------------- level-2: per-bucket node sort + offs/cnt + edge-weight precompute ----
__global__ __launch_bounds__(1024) void k_fine(const unsigned* entries, const int* gbcursor,
                                               int cap, int N,
                                               const float* a_src, const float* a_dst,
                                               int* offs, int* cnt,
                                               uint16_t* ssrc, uint16_t* ews) {
    __shared__ int ncnt[BKT_SZ];
    __shared__ int nscan[BKT_SZ];
    __shared__ int wcur[BKT_SZ];
    const int b = blockIdx.x;
    const int t = threadIdx.x;
    const int node0 = b << BKT_BITS;
    const size_t eb = (size_t)b * cap;
    const int count = min(gbcursor[b], cap);

    if (t < BKT_SZ) ncnt[t] = 0;
    __syncthreads();
    for (int i = t; i < count; i += 1024)
        atomicAdd(&ncnt[entries[eb + i] >> 17], 1);
    __syncthreads();
    if (t < BKT_SZ) nscan[t] = ncnt[t];
    __syncthreads();
    for (int o = 1; o < BKT_SZ; o <<= 1) {
        int v = (t < BKT_SZ && t >= o) ? nscan[t - o] : 0;
        __syncthreads();
        if (t < BKT_SZ) nscan[t] += v;
        __syncthreads();
    }
    if (t < BKT_SZ) {
        int excl = nscan[t] - ncnt[t];
        wcur[t] = excl;
        int node = node0 + t;
        if (node < N) {
            offs[node] = (int)eb + excl;
            cnt[node] = ncnt[t];
        }
    }
    __syncthreads();
    // scatter src + per-head fp16 edge weight e = exp(leaky(a_src[s]+a_dst[d]))
    for (int i = t; i < count; i += 1024) {
        unsigned e = entries[eb + i];
        int dlo = (int)(e >> 17);
        int s = (int)(e & 0x1FFFFu);
        int slot = atomicAdd(&wcur[dlo], 1);
        int d = node0 + dlo;
        float4 as = *(const float4*)(a_src + (size_t)s * 4);
        float4 ad = *(const float4*)(a_dst + (size_t)d * 4);
        float e0 = leaky_exp(as.x + ad.x);
        float e1 = leaky_exp(as.y + ad.y);
        float e2 = leaky_exp(as.z + ad.z);
        float e3 = leaky_exp(as.w + ad.w);
        ssrc[eb + slot] = (uint16_t)s;
        *(uint2*)(ews + (eb + (size_t)slot) * 4) = make_uint2(pack2h(e0, e1), pack2h(e2, e3));
    }
}

// ---------------- per-node aggregation: one wave per node ----------------
__global__ __launch_bounds__(256) void k_aggregate(
    const unsigned* xph, const float* a_src, const float* a_dst,
    const int* offs, const int* cnt, const uint16_t* ssrc, const uint16_t* ews,
    const float* biasf, const int* flags, int N, void* out) {
    int wid = (blockIdx.x * 256 + threadIdx.x) >> 6;
    int lane = threadIdx.x & 63;
    if (wid >= N) return;
    const int n = wid;
    const int h = lane >> 4;        // 2*lane in [32h, 32h+31]
    const int c0 = 2 * lane;
    const unsigned l4 = (unsigned)lane * 4u;
    const char* xb = (const char*)xph;
    const __half* ewh = (const __half*)ews;

    // self loop in fp32
    float adst = a_dst[(size_t)n * 4 + h];
    float e = leaky_exp(a_src[(size_t)n * 4 + h] + adst);
    float2 xw = h2_to_f2(*(const unsigned*)(xb + (unsigned)n * 256u + l4));
    float acc0 = e * xw.x, acc1 = e * xw.y, den = e;

    const int beg = offs[n];
    const int endp = beg + cnt[n];
    int i = beg;
    for (; i + 4 <= endp; i += 4) {
        int s0 = ssrc[i], s1 = ssrc[i + 1], s2 = ssrc[i + 2], s3 = ssrc[i + 3];
        float e0 = __half2float(ewh[(size_t)i * 4 + h]);
        float e1 = __half2float(ewh[(size_t)(i + 1) * 4 + h]);
        float e2 = __half2float(ewh[(size_t)(i + 2) * 4 + h]);
        float e3 = __half2float(ewh[(size_t)(i + 3) * 4 + h]);
        unsigned w0 = *(const unsigned*)(xb + (unsigned)s0 * 256u + l4);
        unsigned w1 = *(const unsigned*)(xb + (unsigned)s1 * 256u + l4);
        unsigned w2 = *(const unsigned*)(xb + (unsigned)s2 * 256u + l4);
        unsigned w3 = *(const unsigned*)(xb + (unsigned)s3 * 256u + l4);
        float2 f0 = h2_to_f2(w0), f1 = h2_to_f2(w1), f2 = h2_to_f2(w2), f3 = h2_to_f2(w3);
        acc0 = fmaf(e0, f0.x, acc0); acc1 = fmaf(e0, f0.y, acc1);
        acc0 = fmaf(e1, f1.x, acc0); acc1 = fmaf(e1, f1.y, acc1);
        acc0 = fmaf(e2, f2.x, acc0); acc1 = fmaf(e2, f2.y, acc1);
        acc0 = fmaf(e3, f3.x, acc0); acc1 = fmaf(e3, f3.y, acc1);
        den += (e0 + e1) + (e2 + e3);
    }
    for (; i < endp; ++i) {
        int s0 = ssrc[i];
        float e0 = __half2float(ewh[(size_t)i * 4 + h]);
        unsigned w0 = *(const unsigned*)(xb + (unsigned)s0 * 256u + l4);
        float2 f0 = h2_to_f2(w0);
        acc0 = fmaf(e0, f0.x, acc0); acc1 = fmaf(e0, f0.y, acc1);
        den += e0;
    }
    float inv = 1.f / (den + 1e-16f);
    float z0 = fmaf(acc0, inv, biasf[c0]);
    float z1 = fmaf(acc1, inv, biasf[c0 + 1]);
    float r0 = MIX_BETA * z0 + (MIX_C - MIX_BETA) * z0 / (1.f + __expf(-z0));
    float r1 = MIX_BETA * z1 + (MIX_C - MIX_BETA) * z1 / (1.f + __expf(-z1));
    if (flags[0]) {
        *(unsigned*)((uint16_t*)out + (size_t)n * 128 + c0) = pack2bf(r0, r1);
    } else {
        *(float2*)((float*)out + (size_t)n * 128 + c0) = make_float2(r0, r1);
    }
}

extern "C" void kernel_launch(void* const* d_in, const int* in_sizes, int n_in,
                              void* d_out, int out_size, void* d_ws, size_t ws_size,
                              hipStream_t stream) {
    const void* x     = d_in[0];
    const void* ei    = d_in[1];
    const void* W     = d_in[2];
    const void* att_s = d_in[3];
    const void* att_d = d_in[4];
    const void* bias  = d_in[5];
    const int N = in_sizes[0] / 128;
    const int E = in_sizes[1] / 2;
    const int NB = (N + BKT_SZ - 1) >> BKT_BITS;
    const int cap = E / NB + E / (8 * NB) + 1024;

    char* ws = (char*)d_ws;
    size_t off = 0;
    auto alloc = [&](size_t bytes) -> void* {
        void* p = ws + off;
        off += (bytes + 255) & ~(size_t)255;
        return p;
    };
    int* flags        = (int*)alloc(16);
    unsigned* entries = (unsigned*)alloc((size_t)NB * cap * 4);
    uint16_t* ssrc    = (uint16_t*)alloc((size_t)NB * cap * 2);
    uint16_t* ews     = (uint16_t*)alloc((size_t)NB * cap * 8);
    int* gbcursor     = (int*)alloc(NBMAX * 4);
    int* offs         = (int*)alloc((size_t)N * 4);
    int* cnt          = (int*)alloc((size_t)N * 4);
    unsigned* xph     = (unsigned*)alloc((size_t)N * 64 * 4);   // fp16 x2 packed
    float* a_src      = (float*)alloc((size_t)N * 4 * 4);
    float* a_dst      = (float*)alloc((size_t)N * 4 * 4);
    float* att_sf     = (float*)alloc(128 * 4);
    float* att_df     = (float*)alloc(128 * 4);
    float* biasf      = (float*)alloc(128 * 4);

    k_detect<<<1, 64, 0, stream>>>(x, ei, N, flags);
    k_canon_small<<<1, 384, 0, stream>>>(att_s, att_d, bias, flags, att_sf, att_df, biasf);
    hipMemsetAsync(gbcursor, 0, NBMAX * 4, stream);
    k_gemm<<<(N + 127) / 128, 256, 0, stream>>>(x, W, att_sf, att_df, flags, N,
                                                xph, a_src, a_dst);
    k_bscatter<<<(E + CH - 1) / CH, 256, 0, stream>>>(ei, E, flags, NB, cap, gbcursor, entries);
    k_fine<<<NB, 1024, 0, stream>>>(entries, gbcursor, cap, N, a_src, a_dst,
                                    offs, cnt, ssrc, ews);
    k_aggregate<<<(N + 3) / 4, 256, 0, stream>>>(xph, a_src, a_dst, offs, cnt, ssrc, ews,
                                                 biasf, flags, N, d_out);
}

// Round 6
// 151.629 us; speedup vs baseline: 2.6338x; 1.1557x over previous
//
#include <hip/hip_runtime.h>
#include <hip/hip_bf16.h>
#include <hip/hip_fp16.h>
#include <stdint.h>

#define LEAKY 0.2f
#define MIX_BETA 0.5f
#define MIX_C 1.2f

#define BKT_BITS 8                 // 256 nodes per bucket
#define BKT_SZ   (1 << BKT_BITS)
#define NBMAX    256               // max buckets
#define CH       4096              // edges per k_bscatter block
#define EPT      16                // edges per thread in k_bscatter (CH/256)

using short8 = __attribute__((ext_vector_type(8))) short;
using f32x4  = __attribute__((ext_vector_type(4))) float;

__device__ __forceinline__ unsigned f2bf(float f) {
    unsigned u = __float_as_uint(f);
    return (u + 0x7fffu + ((u >> 16) & 1u)) >> 16;   // RNE
}
__device__ __forceinline__ unsigned pack2bf(float a, float b) {
    return f2bf(a) | (f2bf(b) << 16);
}
__device__ __forceinline__ float2 h2_to_f2(unsigned u) {
    __half2 h = *reinterpret_cast<__half2*>(&u);
    return __half22float2(h);
}
__device__ __forceinline__ unsigned pack2h(float a, float b) {
    return (unsigned)__half_as_ushort(__float2half(a)) |
           ((unsigned)__half_as_ushort(__float2half(b)) << 16);
}
__device__ __forceinline__ float leaky_exp(float v) {
    v = fmaxf(v, LEAKY * v);
    return __expf(v);
}

// ---------------- prep: dtype detect + canon small vecs + W transpose to bf16 ----------
__global__ __launch_bounds__(512) void k_prep(const void* x, const void* ei, const void* W,
                                              const void* att_s, const void* att_d,
                                              const void* bias, int N, int* flags,
                                              float* att_sf, float* att_df, float* biasf,
                                              uint16_t* Wtg) {
    __shared__ uint16_t wt[128][136];
    __shared__ int lf[2];
    const int t = threadIdx.x;
    if (t < 64) {
        const uint16_t* u = (const uint16_t*)x;
        uint16_t v = u[2 * t];                 // low half if fp32, full elem if bf16
        int ef = (v >> 7) & 0xFF;
        bool ok = (ef >= 90 && ef <= 140);     // plausible N(0,1) bf16 exponent
        unsigned long long all_ok = __ballot(ok);
        const unsigned long long* e64 = (const unsigned long long*)ei;
        bool big = (e64[t] >= (unsigned long long)N);   // int32 pairs pack huge
        unsigned long long anybig = __ballot(big);
        if (t == 0) {
            int f0 = (all_ok == ~0ull) ? 1 : 0;
            int f1 = (anybig != 0ull) ? 1 : 0;
            flags[0] = f0; flags[1] = f1;
            lf[0] = f0; lf[1] = f1;
        }
    }
    __syncthreads();
    const bool bf = lf[0] != 0;
    if (t >= 64 && t < 448) {
        int i = t - 64;
        const void* in; float* out; int idx;
        if (i < 128)      { in = att_s; out = att_sf; idx = i; }
        else if (i < 256) { in = att_d; out = att_df; idx = i - 128; }
        else              { in = bias;  out = biasf;  idx = i - 256; }
        float v = bf ? __uint_as_float(((unsigned)((const uint16_t*)in)[idx]) << 16)
                     : ((const float*)in)[idx];
        out[idx] = v;
    }
    // W [k][n] -> bf16 Wt [n][k]
    for (int s = t; s < 4096; s += 512) {
        int k = s >> 5, c4 = (s & 31) * 4;
        ushort4 hv;
        if (bf) {
            hv = *(const ushort4*)((const uint16_t*)W + k * 128 + c4);
        } else {
            float4 v = *(const float4*)((const float*)W + k * 128 + c4);
            hv.x = (uint16_t)f2bf(v.x); hv.y = (uint16_t)f2bf(v.y);
            hv.z = (uint16_t)f2bf(v.z); hv.w = (uint16_t)f2bf(v.w);
        }
        wt[c4 + 0][k] = hv.x; wt[c4 + 1][k] = hv.y;
        wt[c4 + 2][k] = hv.z; wt[c4 + 3][k] = hv.w;
    }
    __syncthreads();
    for (int s = t; s < 2048; s += 512) {
        int r = s >> 4, ch = (s & 15) * 8;
        *(int4*)(Wtg + r * 128 + ch) = *(const int4*)&wt[r][ch];
    }
}

// ---------------- MFMA GEMM: xp = x @ W (bf16 in, fp32 acc) + fp16 store + logits ------
__global__ __launch_bounds__(256) void k_gemm(const void* x, const uint16_t* Wtg,
                                              const float* att_sf, const float* att_df,
                                              const int* flags, int N,
                                              unsigned* xph, float* a_src, float* a_dst) {
    __shared__ uint16_t xs[128][136];    // bf16 A-tile, then reused as fp16 C-tile
    const bool bf = flags[0] != 0;
    const int t = threadIdx.x;
    const int row0 = blockIdx.x * 128;

    // stage x tile as bf16 (row-clamped)
    for (int s = t; s < 4096; s += 256) {
        int r = s >> 5, kc = (s & 31) * 4;
        int rr = row0 + r; if (rr >= N) rr = N - 1;
        size_t g = (size_t)rr * 128 + kc;
        ushort4 hv;
        if (bf) {
            hv = *(const ushort4*)((const uint16_t*)x + g);
        } else {
            float4 v = *(const float4*)((const float*)x + g);
            hv.x = (uint16_t)f2bf(v.x); hv.y = (uint16_t)f2bf(v.y);
            hv.z = (uint16_t)f2bf(v.z); hv.w = (uint16_t)f2bf(v.w);
        }
        *(ushort4*)&xs[r][kc] = hv;
    }
    __syncthreads();

    const int w = t >> 6, l = t & 63;
    const int rA = l & 15;
    const int kg = (l >> 4) * 8;
    f32x4 acc[2][8];
#pragma unroll
    for (int fr = 0; fr < 2; ++fr)
#pragma unroll
        for (int fc = 0; fc < 8; ++fc) acc[fr][fc] = (f32x4){0.f, 0.f, 0.f, 0.f};

#pragma unroll
    for (int kk = 0; kk < 4; ++kk) {
        const int kb = kk * 32 + kg;
        short8 a0 = *(const short8*)&xs[w * 32 + rA][kb];
        short8 a1 = *(const short8*)&xs[w * 32 + 16 + rA][kb];
        const uint16_t* wp = Wtg + rA * 128 + kb;
#pragma unroll
        for (int fc = 0; fc < 8; ++fc) {
            short8 b = *(const short8*)(wp + fc * 2048);    // Wt[16*fc + rA][kb..]
            acc[0][fc] = __builtin_amdgcn_mfma_f32_16x16x32_bf16(a0, b, acc[0][fc], 0, 0, 0);
            acc[1][fc] = __builtin_amdgcn_mfma_f32_16x16x32_bf16(a1, b, acc[1][fc], 0, 0, 0);
        }
    }
    __syncthreads();   // all A-reads done; reuse xs as fp16 C buffer

    // C/D layout (m89): col = lane&15, row = (lane>>4)*4 + reg
#pragma unroll
    for (int fr = 0; fr < 2; ++fr)
#pragma unroll
        for (int fc = 0; fc < 8; ++fc) {
            int row = w * 32 + fr * 16 + (l >> 4) * 4;
            int col = fc * 16 + rA;
#pragma unroll
            for (int j = 0; j < 4; ++j)
                xs[row + j][col] = __half_as_ushort(__float2half(acc[fr][fc][j]));
        }
    __syncthreads();

    // epilogue 1: coalesced fp16 xp store
    for (int s = t; s < 2048; s += 256) {
        int r = s >> 4, ch = (s & 15) * 8;
        int rr = row0 + r;
        if (rr < N)
            *(int4*)((uint16_t*)xph + (size_t)rr * 128 + ch) = *(const int4*)&xs[r][ch];
    }
    // epilogue 2: attention logits (512 items = 128 rows x 4 heads)
    for (int s = t; s < 512; s += 256) {
        int r = s >> 2, hh = s & 3;
        int rr = row0 + r;
        if (rr < N) {
            float ss = 0.f, sd = 0.f;
#pragma unroll
            for (int q = 0; q < 32; ++q) {
                float v = __half2float(__ushort_as_half(xs[r][hh * 32 + q]));
                ss = fmaf(v, att_sf[hh * 32 + q], ss);
                sd = fmaf(v, att_df[hh * 32 + q], sd);
            }
            a_src[(size_t)rr * 4 + hh] = ss;
            a_dst[(size_t)rr * 4 + hh] = sd;
        }
    }
}

// ---------------- level-1 scatter into fixed-capacity bucket segments ----------------
__global__ __launch_bounds__(256) void k_bscatter(const void* ei, int E, const int* flags,
                                                  int nb, int cap, int* gbcursor,
                                                  unsigned* entries) {
    __shared__ int lcnt[NBMAX];
    __shared__ int loff[NBMAX];
    __shared__ int lbase[NBMAX];
    __shared__ int wcur[NBMAX];
    __shared__ int sc[NBMAX];
    __shared__ unsigned st[CH];
    __shared__ uint8_t bb[CH];
    const bool is32 = flags[1] != 0;
    const int t = threadIdx.x;
    const int chunk0 = blockIdx.x * CH;
    const int nvalid = min(CH, E - chunk0);

    int se[EPT], de[EPT];
    lcnt[t] = 0; wcur[t] = 0;
    __syncthreads();
#pragma unroll
    for (int k = 0; k < EPT; ++k) {
        int i = chunk0 + k * 256 + t;
        if (i < E) {
            int s, d;
            if (is32) { const int* p = (const int*)ei; s = p[i]; d = p[E + i]; }
            else { const long long* p = (const long long*)ei; s = (int)p[i]; d = (int)p[E + i]; }
            se[k] = s; de[k] = d;
            atomicAdd(&lcnt[d >> BKT_BITS], 1);
        } else {
            de[k] = -1;
        }
    }
    __syncthreads();
    sc[t] = lcnt[t];
    __syncthreads();
    for (int o = 1; o < NBMAX; o <<= 1) {
        int w = (t >= o) ? sc[t - o] : 0;
        __syncthreads();
        sc[t] += w;
        __syncthreads();
    }
    if (t < nb) {
        loff[t] = sc[t] - lcnt[t];
        if (lcnt[t]) {
            int base = atomicAdd(&gbcursor[t], lcnt[t]);
            if (base + lcnt[t] > cap) base = cap - lcnt[t];   // memory-safety clamp
            lbase[t] = base;
        }
    }
    __syncthreads();
#pragma unroll
    for (int k = 0; k < EPT; ++k) {
        int d = de[k];
        if (d >= 0) {
            int b = d >> BKT_BITS;
            int slot = atomicAdd(&wcur[b], 1);
            int pos = loff[b] + slot;
            st[pos] = (unsigned)se[k] | ((unsigned)(d & (BKT_SZ - 1)) << 17);
            bb[pos] = (uint8_t)b;
        }
    }
    __syncthreads();
    for (int s = t; s < nvalid; s += 256) {
        int b = bb[s];
        entries[(size_t)b * cap + lbase[b] + (s - loff[b])] = st[s];
    }
}

// ---------------- level-2: per-bucket node sort + offs/cnt + edge-weight precompute ----
__global__ __launch_bounds__(1024) void k_fine(const unsigned* entries, const int* gbcursor,
                                               int cap, int N,
                                               const float* a_src, const float* a_dst,
                                               int* offs, int* cnt,
                                               uint16_t* ssrc, uint16_t* ews) {
    __shared__ int ncnt[BKT_SZ];
    __shared__ int nscan[BKT_SZ];
    __shared__ int wcur[BKT_SZ];
    const int b = blockIdx.x;
    const int t = threadIdx.x;
    const int node0 = b << BKT_BITS;
    const size_t eb = (size_t)b * cap;
    const int count = min(gbcursor[b], cap);

    if (t < BKT_SZ) ncnt[t] = 0;
    __syncthreads();
    for (int i = t; i < count; i += 1024)
        atomicAdd(&ncnt[entries[eb + i] >> 17], 1);
    __syncthreads();
    if (t < BKT_SZ) nscan[t] = ncnt[t];
    __syncthreads();
    for (int o = 1; o < BKT_SZ; o <<= 1) {
        int v = (t < BKT_SZ && t >= o) ? nscan[t - o] : 0;
        __syncthreads();
        if (t < BKT_SZ) nscan[t] += v;
        __syncthreads();
    }
    if (t < BKT_SZ) {
        int excl = nscan[t] - ncnt[t];
        wcur[t] = excl;
        int node = node0 + t;
        if (node < N) {
            offs[node] = (int)eb + excl;
            cnt[node] = ncnt[t];
        }
    }
    __syncthreads();
    for (int i = t; i < count; i += 1024) {
        unsigned e = entries[eb + i];
        int dlo = (int)(e >> 17);
        int s = (int)(e & 0x1FFFFu);
        int slot = atomicAdd(&wcur[dlo], 1);
        int d = node0 + dlo;
        float4 as = *(const float4*)(a_src + (size_t)s * 4);
        float4 ad = *(const float4*)(a_dst + (size_t)d * 4);
        float e0 = leaky_exp(as.x + ad.x);
        float e1 = leaky_exp(as.y + ad.y);
        float e2 = leaky_exp(as.z + ad.z);
        float e3 = leaky_exp(as.w + ad.w);
        ssrc[eb + slot] = (uint16_t)s;
        *(uint2*)(ews + (eb + (size_t)slot) * 4) = make_uint2(pack2h(e0, e1), pack2h(e2, e3));
    }
}

// ---------------- per-node aggregation: one wave per node ----------------
__global__ __launch_bounds__(256) void k_aggregate(
    const unsigned* xph, const float* a_src, const float* a_dst,
    const int* offs, const int* cnt, const uint16_t* ssrc, const uint16_t* ews,
    const float* biasf, const int* flags, int N, void* out) {
    int wid = (blockIdx.x * 256 + threadIdx.x) >> 6;
    int lane = threadIdx.x & 63;
    if (wid >= N) return;
    const int n = wid;
    const int h = lane >> 4;        // 2*lane in [32h, 32h+31]
    const int c0 = 2 * lane;
    const unsigned l4 = (unsigned)lane * 4u;
    const char* xb = (const char*)xph;
    const __half* ewh = (const __half*)ews;

    float adst = a_dst[(size_t)n * 4 + h];
    float e = leaky_exp(a_src[(size_t)n * 4 + h] + adst);
    float2 xw = h2_to_f2(*(const unsigned*)(xb + (unsigned)n * 256u + l4));
    float acc0 = e * xw.x, acc1 = e * xw.y, den = e;

    const int beg = offs[n];
    const int endp = beg + cnt[n];
    int i = beg;
    for (; i + 4 <= endp; i += 4) {
        int s0 = ssrc[i], s1 = ssrc[i + 1], s2 = ssrc[i + 2], s3 = ssrc[i + 3];
        float e0 = __half2float(ewh[(size_t)i * 4 + h]);
        float e1 = __half2float(ewh[(size_t)(i + 1) * 4 + h]);
        float e2 = __half2float(ewh[(size_t)(i + 2) * 4 + h]);
        float e3 = __half2float(ewh[(size_t)(i + 3) * 4 + h]);
        unsigned w0 = *(const unsigned*)(xb + (unsigned)s0 * 256u + l4);
        unsigned w1 = *(const unsigned*)(xb + (unsigned)s1 * 256u + l4);
        unsigned w2 = *(const unsigned*)(xb + (unsigned)s2 * 256u + l4);
        unsigned w3 = *(const unsigned*)(xb + (unsigned)s3 * 256u + l4);
        float2 f0 = h2_to_f2(w0), f1 = h2_to_f2(w1), f2 = h2_to_f2(w2), f3 = h2_to_f2(w3);
        acc0 = fmaf(e0, f0.x, acc0); acc1 = fmaf(e0, f0.y, acc1);
        acc0 = fmaf(e1, f1.x, acc0); acc1 = fmaf(e1, f1.y, acc1);
        acc0 = fmaf(e2, f2.x, acc0); acc1 = fmaf(e2, f2.y, acc1);
        acc0 = fmaf(e3, f3.x, acc0); acc1 = fmaf(e3, f3.y, acc1);
        den += (e0 + e1) + (e2 + e3);
    }
    for (; i < endp; ++i) {
        int s0 = ssrc[i];
        float e0 = __half2float(ewh[(size_t)i * 4 + h]);
        unsigned w0 = *(const unsigned*)(xb + (unsigned)s0 * 256u + l4);
        float2 f0 = h2_to_f2(w0);
        acc0 = fmaf(e0, f0.x, acc0); acc1 = fmaf(e0, f0.y, acc1);
        den += e0;
    }
    float inv = 1.f / (den + 1e-16f);
    float z0 = fmaf(acc0, inv, biasf[c0]);
    float z1 = fmaf(acc1, inv, biasf[c0 + 1]);
    float r0 = MIX_BETA * z0 + (MIX_C - MIX_BETA) * z0 / (1.f + __expf(-z0));
    float r1 = MIX_BETA * z1 + (MIX_C - MIX_BETA) * z1 / (1.f + __expf(-z1));
    if (flags[0]) {
        *(unsigned*)((uint16_t*)out + (size_t)n * 128 + c0) = pack2bf(r0, r1);
    } else {
        *(float2*)((float*)out + (size_t)n * 128 + c0) = make_float2(r0, r1);
    }
}

extern "C" void kernel_launch(void* const* d_in, const int* in_sizes, int n_in,
                              void* d_out, int out_size, void* d_ws, size_t ws_size,
                              hipStream_t stream) {
    const void* x     = d_in[0];
    const void* ei    = d_in[1];
    const void* W     = d_in[2];
    const void* att_s = d_in[3];
    const void* att_d = d_in[4];
    const void* bias  = d_in[5];
    const int N = in_sizes[0] / 128;
    const int E = in_sizes[1] / 2;
    const int NB = (N + BKT_SZ - 1) >> BKT_BITS;
    const int cap = E / NB + E / (8 * NB) + 1024;

    char* ws = (char*)d_ws;
    size_t off = 0;
    auto alloc = [&](size_t bytes) -> void* {
        void* p = ws + off;
        off += (bytes + 255) & ~(size_t)255;
        return p;
    };
    int* flags        = (int*)alloc(16);
    unsigned* entries = (unsigned*)alloc((size_t)NB * cap * 4);
    uint16_t* ssrc    = (uint16_t*)alloc((size_t)NB * cap * 2);
    uint16_t* ews     = (uint16_t*)alloc((size_t)NB * cap * 8);
    int* gbcursor     = (int*)alloc(NBMAX * 4);
    int* offs         = (int*)alloc((size_t)N * 4);
    int* cnt          = (int*)alloc((size_t)N * 4);
    unsigned* xph     = (unsigned*)alloc((size_t)N * 64 * 4);   // fp16 x2 packed
    float* a_src      = (float*)alloc((size_t)N * 4 * 4);
    float* a_dst      = (float*)alloc((size_t)N * 4 * 4);
    float* att_sf     = (float*)alloc(128 * 4);
    float* att_df     = (float*)alloc(128 * 4);
    float* biasf      = (float*)alloc(128 * 4);
    uint16_t* Wtg     = (uint16_t*)alloc(128 * 128 * 2);        // bf16 W^T [n][k]

    k_prep<<<1, 512, 0, stream>>>(x, ei, W, att_s, att_d, bias, N, flags,
                                  att_sf, att_df, biasf, Wtg);
    hipMemsetAsync(gbcursor, 0, NBMAX * 4, stream);
    k_gemm<<<(N + 127) / 128, 256, 0, stream>>>(x, Wtg, att_sf, att_df, flags, N,
                                                xph, a_src, a_dst);
    k_bscatter<<<(E + CH - 1) / CH, 256, 0, stream>>>(ei, E, flags, NB, cap, gbcursor, entries);
    k_fine<<<NB, 1024, 0, stream>>>(entries, gbcursor, cap, N, a_src, a_dst,
                                    offs, cnt, ssrc, ews);
    k_aggregate<<<(N + 3) / 4, 256, 0, stream>>>(xph, a_src, a_dst, offs, cnt, ssrc, ews,
                                                 biasf, flags, N, d_out);
}